// Round 3
// baseline (1129.819 us; speedup 1.0000x reference)
//
#include <hip/hip_runtime.h>
#include <hip/hip_bf16.h>

typedef unsigned short u16;
typedef __attribute__((ext_vector_type(8))) short short8;   // 8 bf16 (4 VGPRs)
typedef __attribute__((ext_vector_type(4))) float f32x4;

#define NTOK 740
#define NTMP 256
#define NTGT 484
#define DM   512
#define MH   8
#define MROWS 11840   // B*NTOK = 16*740

__device__ __forceinline__ float b2f(u16 u) {
    union { unsigned int i; float f; } x; x.i = ((unsigned int)u) << 16; return x.f;
}
__device__ __forceinline__ u16 f2b(float f) {
    union { float f; unsigned int i; } x; x.f = f;
    unsigned int r = x.i + 0x7FFFu + ((x.i >> 16) & 1u);   // RNE
    return (u16)(r >> 16);
}
struct alignas(8) us4 { u16 x, y, z, w; };
__device__ __forceinline__ float4 ld4bf(const u16* p) {
    us4 u = *(const us4*)p;
    return float4{b2f(u.x), b2f(u.y), b2f(u.z), b2f(u.w)};
}

// -------- weight transpose + bf16 convert: WT[n][k] = W[k][n], 512x512 --------
__global__ __launch_bounds__(256) void transpose512(const float* __restrict__ W,
                                                    u16* __restrict__ WT) {
    __shared__ float t[32][33];
    int bx = blockIdx.x, by = blockIdx.y;
    int tx = threadIdx.x;           // 0..31
    for (int i = threadIdx.y; i < 32; i += 8)
        t[i][tx] = W[(size_t)(by * 32 + i) * 512 + bx * 32 + tx];
    __syncthreads();
    for (int i = threadIdx.y; i < 32; i += 8)
        WT[(size_t)(bx * 32 + i) * 512 + by * 32 + tx] = f2b(t[tx][i]);
}

// ---------------- depthwise 3x3 conv + BN (one branch), f32 in -> bf16 out ----
__global__ __launch_bounds__(256) void conv_bn(const float* __restrict__ x,
                                               const float* __restrict__ cw,
                                               const float* __restrict__ g,
                                               const float* __restrict__ bb,
                                               const float* __restrict__ m,
                                               const float* __restrict__ v,
                                               u16* __restrict__ out) {
    int bn = blockIdx.x;
    int b = bn / NTOK, n = bn % NTOK;
    bool tmp = n < NTMP;
    int L = tmp ? 16 : 22, base = tmp ? 0 : NTMP, p = n - base;
    int ph = p / L, pw = p % L;
    int nb[9]; bool ok[9];
#pragma unroll
    for (int tap = 0; tap < 9; ++tap) {
        int dh = tap / 3 - 1, dw = tap % 3 - 1;
        int h2 = ph + dh, w2 = pw + dw;
        ok[tap] = (h2 >= 0 && h2 < L && w2 >= 0 && w2 < L);
        nb[tap] = ok[tap] ? (b * NTOK + base + h2 * L + w2) : 0;
    }
    for (int c = threadIdx.x; c < DM; c += 256) {
        float acc = 0.f;
#pragma unroll
        for (int tap = 0; tap < 9; ++tap)
            if (ok[tap]) acc = fmaf(cw[c * 9 + tap], x[(size_t)nb[tap] * DM + c], acc);
        float inv = g[c] * rsqrtf(v[c] + 1e-5f);
        out[(size_t)bn * DM + c] = f2b((acc - m[c]) * inv + bb[c]);
    }
}

// ---------------- MFMA GEMM: C[M,512] = A[M,512] @ BT^T + bias ----------------
// A row-major [M,512] bf16, BT row-major [512,512] bf16 (BT[n][k] = B[k][n]).
// bias f32. Output: bf16 (OT=u16) or f32 (OT=float).
template <typename OT>
__global__ __launch_bounds__(256) void gemm_bias(const u16* __restrict__ A,
                                                 const u16* __restrict__ BT,
                                                 const float* __restrict__ bias,
                                                 OT* __restrict__ C, int M) {
    __shared__ u16 As[128][40];   // +8 pad: varied banks for frag reads
    __shared__ u16 Bs[128][40];
    const int tid = threadIdx.x;
    const int gm0 = blockIdx.x * 128;
    const int gn0 = blockIdx.y * 128;
    const int lane = tid & 63;
    const int wid = tid >> 6;
    const int wm = (wid >> 1) * 64, wn = (wid & 1) * 64;
    const int lr = lane & 15, lk = (lane >> 4) * 8;
    const int r = tid >> 2;             // 0..63
    const int cg = (tid & 3) * 8;       // 0,8,16,24
    f32x4 acc[4][4] = {};

    for (int kt = 0; kt < 16; ++kt) {
        const int k0 = kt * 32;
        __syncthreads();
        for (int rr = r; rr < 128; rr += 64) {
            int gr = gm0 + rr;
            int4 av;
            if (gr < M) av = *(const int4*)(A + (size_t)gr * 512 + k0 + cg);
            else av = int4{0, 0, 0, 0};
            *(int4*)&As[rr][cg] = av;
            int4 bv = *(const int4*)(BT + (size_t)(gn0 + rr) * 512 + k0 + cg);
            *(int4*)&Bs[rr][cg] = bv;
        }
        __syncthreads();
        short8 af[4], bfr[4];
#pragma unroll
        for (int i = 0; i < 4; ++i) {
            af[i]  = *(const short8*)&As[wm + i * 16 + lr][lk];
            bfr[i] = *(const short8*)&Bs[wn + i * 16 + lr][lk];
        }
#pragma unroll
        for (int i = 0; i < 4; ++i)
#pragma unroll
            for (int j = 0; j < 4; ++j)
                acc[i][j] = __builtin_amdgcn_mfma_f32_16x16x32_bf16(af[i], bfr[j], acc[i][j], 0, 0, 0);
    }
    const int orow = (lane >> 4) * 4;
#pragma unroll
    for (int i = 0; i < 4; ++i)
#pragma unroll
        for (int j = 0; j < 4; ++j) {
            const int gc = gn0 + wn + j * 16 + lr;
            const float bv = bias[gc];
#pragma unroll
            for (int rr2 = 0; rr2 < 4; ++rr2) {
                const int gr = gm0 + wm + i * 16 + orow + rr2;
                if (gr < M) {
                    const float val = acc[i][j][rr2] + bv;
                    if constexpr (sizeof(OT) == 2) C[(size_t)gr * 512 + gc] = (OT)f2b(val);
                    else                           C[(size_t)gr * 512 + gc] = (OT)val;
                }
            }
        }
}

// ---------------- attention (VALU, 16 q-rows per pass) ----------------
template <bool TARGET>
__global__ __launch_bounds__(256) void attn_kernel(const u16* __restrict__ qb,
                                                   const u16* __restrict__ kb,
                                                   const u16* __restrict__ vb,
                                                   const float* __restrict__ rpb,
                                                   const float* __restrict__ tt,
                                                   const float* __restrict__ tg,
                                                   u16* __restrict__ attb) {
    constexpr int NK   = TARGET ? NTOK : NTMP;
    constexpr int NKP  = NK + 4;
    constexpr int QTOT = TARGET ? NTGT : NTMP;
    constexpr int CHUNK = TARGET ? 121 : 64;   // 4 chunks cover QTOT
    constexpr int QOFF = TARGET ? NTMP : 0;
    constexpr int L = TARGET ? 22 : 16;
    constexpr int RR = 2 * L - 1;

    __shared__ float qs[16][64];
    __shared__ float sc[16][NKP];
    __shared__ float rsum[16];

    const int b = blockIdx.z, h = blockIdx.y;
    const int row0 = blockIdx.x * CHUNK;
    const int tid = threadIdx.x;
    const size_t brow = (size_t)b * NTOK;

    for (int p0 = 0; p0 < CHUNK; p0 += 16) {
        const int nrows = (CHUNK - p0 < 16) ? (CHUNK - p0) : 16;
        const int qrow0 = row0 + p0;

        for (int i = tid; i < 16 * 64; i += 256) {
            int qr = i >> 6, d = i & 63;
            qs[qr][d] = (qr < nrows)
                ? b2f(qb[(brow + QOFF + qrow0 + qr) * DM + h * 64 + d]) : 0.f;
        }
        __syncthreads();

        int qh_[16], qw_[16];
#pragma unroll
        for (int qr = 0; qr < 16; ++qr) {
            int qrow = qrow0 + qr; if (qrow > QTOT - 1) qrow = QTOT - 1;
            qh_[qr] = qrow / L; qw_[qr] = qrow % L;
        }

        // ---- scores ----
        {
            float a0[16], a1[16];
            const int j0 = tid;
            if constexpr (TARGET) {
                const int j1 = tid + 256;                 // always a target key
                const u16* k0p = kb + (brow + j0) * DM + h * 64;
                const u16* k1p = kb + (brow + j1) * DM + h * 64;
#pragma unroll
                for (int qr = 0; qr < 16; ++qr) { a0[qr] = 0.f; a1[qr] = 0.f; }
                for (int d = 0; d < 64; d += 4) {
                    float4 kv0 = ld4bf(k0p + d);
                    float4 kv1 = ld4bf(k1p + d);
#pragma unroll
                    for (int qr = 0; qr < 16; ++qr) {
                        const float4 qv = *(const float4*)&qs[qr][d];
                        a0[qr] = fmaf(kv0.w, qv.w, fmaf(kv0.z, qv.z, fmaf(kv0.y, qv.y, fmaf(kv0.x, qv.x, a0[qr]))));
                        a1[qr] = fmaf(kv1.w, qv.w, fmaf(kv1.z, qv.z, fmaf(kv1.y, qv.y, fmaf(kv1.x, qv.x, a1[qr]))));
                    }
                }
                const float tt0 = tt[h * NTMP + j0];
                const int kj = j1 - NTMP;
                const int kh = kj / L, kw = kj % L;
#pragma unroll
                for (int qr = 0; qr < 16; ++qr) {
                    int qrow = qrow0 + qr; if (qrow > QTOT - 1) qrow = QTOT - 1;
                    sc[qr][j0] = a0[qr] * 0.125f + tt0 + tg[h * NTGT + qrow];
                    int idx = (qh_[qr] - kh + (L - 1)) * RR + (qw_[qr] - kw + (L - 1));
                    sc[qr][j1] = a1[qr] * 0.125f + rpb[idx * MH + h];
                }
                const int j2 = tid + 512;
                if (j2 < NTOK) {
                    const u16* k2p = kb + (brow + j2) * DM + h * 64;
#pragma unroll
                    for (int qr = 0; qr < 16; ++qr) a0[qr] = 0.f;
                    for (int d = 0; d < 64; d += 4) {
                        float4 kv2 = ld4bf(k2p + d);
#pragma unroll
                        for (int qr = 0; qr < 16; ++qr) {
                            const float4 qv = *(const float4*)&qs[qr][d];
                            a0[qr] = fmaf(kv2.w, qv.w, fmaf(kv2.z, qv.z, fmaf(kv2.y, qv.y, fmaf(kv2.x, qv.x, a0[qr]))));
                        }
                    }
                    const int kj2 = j2 - NTMP;
                    const int kh2 = kj2 / L, kw2 = kj2 % L;
#pragma unroll
                    for (int qr = 0; qr < 16; ++qr) {
                        int idx = (qh_[qr] - kh2 + (L - 1)) * RR + (qw_[qr] - kw2 + (L - 1));
                        sc[qr][j2] = a0[qr] * 0.125f + rpb[idx * MH + h];
                    }
                }
            } else {
                const u16* k0p = kb + (brow + j0) * DM + h * 64;
#pragma unroll
                for (int qr = 0; qr < 16; ++qr) a0[qr] = 0.f;
                for (int d = 0; d < 64; d += 4) {
                    float4 kv0 = ld4bf(k0p + d);
#pragma unroll
                    for (int qr = 0; qr < 16; ++qr) {
                        const float4 qv = *(const float4*)&qs[qr][d];
                        a0[qr] = fmaf(kv0.w, qv.w, fmaf(kv0.z, qv.z, fmaf(kv0.y, qv.y, fmaf(kv0.x, qv.x, a0[qr]))));
                    }
                }
                const int kh = j0 >> 4, kw = j0 & 15;
#pragma unroll
                for (int qr = 0; qr < 16; ++qr) {
                    int idx = (qh_[qr] - kh + (L - 1)) * RR + (qw_[qr] - kw + (L - 1));
                    sc[qr][j0] = a0[qr] * 0.125f + rpb[idx];
                }
                (void)a1;
            }
        }
        __syncthreads();

        // ---- softmax: 16 groups of 16 lanes, blocked j-ranges ----
        {
            const int qr = tid >> 4, l16 = tid & 15;
            constexpr int BLK = (NK + 15) / 16;
            const int jb = l16 * BLK;
            const int je = (jb + BLK < NK) ? jb + BLK : NK;
            float mx = -1e30f;
            for (int j = jb; j < je; ++j) mx = fmaxf(mx, sc[qr][j]);
#pragma unroll
            for (int o = 8; o; o >>= 1) mx = fmaxf(mx, __shfl_xor(mx, o));
            float s = 0.f;
            for (int j = jb; j < je; ++j) {
                const float e = __expf(sc[qr][j] - mx);
                sc[qr][j] = e; s += e;
            }
#pragma unroll
            for (int o = 8; o; o >>= 1) s += __shfl_xor(s, o);
            if (l16 == 0) rsum[qr] = s;
        }
        __syncthreads();

        // ---- PV ----
        {
            const int d = tid & 63, jg = tid >> 6;   // jg uniform per wave -> prob reads broadcast
            float acc[16];
#pragma unroll
            for (int qr = 0; qr < 16; ++qr) acc[qr] = 0.f;
            for (int j = jg; j < NK; j += 4) {
                const float vv = b2f(vb[(brow + j) * DM + h * 64 + d]);
#pragma unroll
                for (int qr = 0; qr < 16; ++qr) acc[qr] = fmaf(sc[qr][j], vv, acc[qr]);
            }
            __syncthreads();   // everyone done reading probs before overwrite
#pragma unroll
            for (int qr = 0; qr < 16; ++qr) sc[qr][jg * 64 + d] = acc[qr];
        }
        __syncthreads();
        for (int i = tid; i < 16 * 64; i += 256) {
            const int qr = i >> 6, d = i & 63;
            if (qr < nrows) {
                const float o = (sc[qr][d] + sc[qr][64 + d] + sc[qr][128 + d] + sc[qr][192 + d]) / rsum[qr];
                attb[(brow + QOFF + qrow0 + qr) * DM + h * 64 + d] = f2b(o);
            }
        }
        __syncthreads();
    }
}

// ---------------- launch ----------------
extern "C" void kernel_launch(void* const* d_in, const int* in_sizes, int n_in,
                              void* d_out, int out_size, void* d_ws, size_t ws_size,
                              hipStream_t stream) {
    const float* x = (const float*)d_in[0];
    const float* convw[3] = {(const float*)d_in[1], (const float*)d_in[6], (const float*)d_in[11]};
    const float* bng[3]   = {(const float*)d_in[2], (const float*)d_in[7], (const float*)d_in[12]};
    const float* bnb[3]   = {(const float*)d_in[3], (const float*)d_in[8], (const float*)d_in[13]};
    const float* bnm[3]   = {(const float*)d_in[4], (const float*)d_in[9], (const float*)d_in[14]};
    const float* bnv[3]   = {(const float*)d_in[5], (const float*)d_in[10], (const float*)d_in[15]};
    const float* w[4]     = {(const float*)d_in[16], (const float*)d_in[18], (const float*)d_in[20], (const float*)d_in[22]};
    const float* bias[4]  = {(const float*)d_in[17], (const float*)d_in[19], (const float*)d_in[21], (const float*)d_in[23]};
    const float* rpb_t = (const float*)d_in[24];
    const float* rpb_m = (const float*)d_in[25];
    const float* tt    = (const float*)d_in[26];
    const float* tg    = (const float*)d_in[27];

    char* ws = (char*)d_ws;
    // layout: 4x wT (512KB each, bf16) | cb/attb | qb | kb | vb (bf16 seqs)
    u16* wT[4];
    for (int i = 0; i < 4; ++i) wT[i] = (u16*)(ws + (size_t)i * 524288);
    const size_t SEQ = (size_t)MROWS * DM * 2;   // 12,124,160 B
    u16* cb = (u16*)(ws + 2097152);
    u16* qb = (u16*)(ws + 2097152 + SEQ);
    u16* kb = (u16*)(ws + 2097152 + 2 * SEQ);
    u16* vb = (u16*)(ws + 2097152 + 3 * SEQ);
    u16* attb = cb;   // cb is dead after the 3rd GEMM; reuse for attention output

    for (int i = 0; i < 4; ++i)
        transpose512<<<dim3(16, 16), dim3(32, 8), 0, stream>>>(w[i], wT[i]);

    u16* qkv[3] = {qb, kb, vb};
    for (int br = 0; br < 3; ++br) {
        conv_bn<<<MROWS, 256, 0, stream>>>(x, convw[br], bng[br], bnb[br], bnm[br], bnv[br], cb);
        gemm_bias<u16><<<dim3(93, 4), 256, 0, stream>>>(cb, wT[br], bias[br], qkv[br], MROWS);
    }
    attn_kernel<true><<<dim3(4, 8, 16), 256, 0, stream>>>(qb, kb, vb, rpb_t, tt, tg, attb);
    attn_kernel<false><<<dim3(4, 8, 16), 256, 0, stream>>>(qb, kb, vb, rpb_m, nullptr, nullptr, attb);
    gemm_bias<float><<<dim3(93, 4), 256, 0, stream>>>(attb, wT[3], bias[3], (float*)d_out, MROWS);
}

// Round 4
// 370.800 us; speedup vs baseline: 3.0470x; 3.0470x over previous
//
#include <hip/hip_runtime.h>
#include <hip/hip_bf16.h>

typedef unsigned short u16;
typedef __attribute__((ext_vector_type(8))) short short8;   // 8 bf16 (4 VGPRs)
typedef __attribute__((ext_vector_type(4))) float f32x4;

#define NTOK 740
#define NTMP 256
#define NTGT 484
#define DM   512
#define MH   8
#define MROWS 11840   // B*NTOK = 16*740
#define KPAD 768      // keys padded to chunk multiple

__device__ __forceinline__ float b2f(u16 u) {
    union { unsigned int i; float f; } x; x.i = ((unsigned int)u) << 16; return x.f;
}
__device__ __forceinline__ u16 f2b(float f) {
    union { float f; unsigned int i; } x; x.f = f;
    unsigned int r = x.i + 0x7FFFu + ((x.i >> 16) & 1u);   // RNE
    return (u16)(r >> 16);
}
struct alignas(8) us4 { u16 x, y, z, w; };

// -------- weight transpose + bf16 convert: WT[n][k] = W[k][n], 512x512 --------
__global__ __launch_bounds__(256) void transpose512(const float* __restrict__ W,
                                                    u16* __restrict__ WT) {
    __shared__ float t[32][33];
    int bx = blockIdx.x, by = blockIdx.y;
    int tx = threadIdx.x;           // 0..31
    for (int i = threadIdx.y; i < 32; i += 8)
        t[i][tx] = W[(size_t)(by * 32 + i) * 512 + bx * 32 + tx];
    __syncthreads();
    for (int i = threadIdx.y; i < 32; i += 8)
        WT[(size_t)(bx * 32 + i) * 512 + by * 32 + tx] = f2b(t[tx][i]);
}

// ---------------- depthwise 3x3 conv + BN (one branch), f32 in -> bf16 out ----
__global__ __launch_bounds__(256) void conv_bn(const float* __restrict__ x,
                                               const float* __restrict__ cw,
                                               const float* __restrict__ g,
                                               const float* __restrict__ bb,
                                               const float* __restrict__ m,
                                               const float* __restrict__ v,
                                               u16* __restrict__ out) {
    int bn = blockIdx.x;
    int b = bn / NTOK, n = bn % NTOK;
    bool tmp = n < NTMP;
    int L = tmp ? 16 : 22, base = tmp ? 0 : NTMP, p = n - base;
    int ph = p / L, pw = p % L;
    int nb[9]; bool ok[9];
#pragma unroll
    for (int tap = 0; tap < 9; ++tap) {
        int dh = tap / 3 - 1, dw = tap % 3 - 1;
        int h2 = ph + dh, w2 = pw + dw;
        ok[tap] = (h2 >= 0 && h2 < L && w2 >= 0 && w2 < L);
        nb[tap] = ok[tap] ? (b * NTOK + base + h2 * L + w2) : 0;
    }
    for (int c = threadIdx.x; c < DM; c += 256) {
        float acc = 0.f;
#pragma unroll
        for (int tap = 0; tap < 9; ++tap)
            if (ok[tap]) acc = fmaf(cw[c * 9 + tap], x[(size_t)nb[tap] * DM + c], acc);
        float inv = g[c] * rsqrtf(v[c] + 1e-5f);
        out[(size_t)bn * DM + c] = f2b((acc - m[c]) * inv + bb[c]);
    }
}

// ---------------- MFMA GEMM: C[M,512] = A[M,512] @ BT^T + bias ----------------
template <typename OT>
__global__ __launch_bounds__(256) void gemm_bias(const u16* __restrict__ A,
                                                 const u16* __restrict__ BT,
                                                 const float* __restrict__ bias,
                                                 OT* __restrict__ C, int M) {
    __shared__ u16 As[128][40];
    __shared__ u16 Bs[128][40];
    const int tid = threadIdx.x;
    const int gm0 = blockIdx.x * 128;
    const int gn0 = blockIdx.y * 128;
    const int lane = tid & 63;
    const int wid = tid >> 6;
    const int wm = (wid >> 1) * 64, wn = (wid & 1) * 64;
    const int lr = lane & 15, lk = (lane >> 4) * 8;
    const int r = tid >> 2;
    const int cg = (tid & 3) * 8;
    f32x4 acc[4][4] = {};

    for (int kt = 0; kt < 16; ++kt) {
        const int k0 = kt * 32;
        __syncthreads();
        for (int rr = r; rr < 128; rr += 64) {
            int gr = gm0 + rr;
            int4 av;
            if (gr < M) av = *(const int4*)(A + (size_t)gr * 512 + k0 + cg);
            else av = int4{0, 0, 0, 0};
            *(int4*)&As[rr][cg] = av;
            int4 bv = *(const int4*)(BT + (size_t)(gn0 + rr) * 512 + k0 + cg);
            *(int4*)&Bs[rr][cg] = bv;
        }
        __syncthreads();
        short8 af[4], bfr[4];
#pragma unroll
        for (int i = 0; i < 4; ++i) {
            af[i]  = *(const short8*)&As[wm + i * 16 + lr][lk];
            bfr[i] = *(const short8*)&Bs[wn + i * 16 + lr][lk];
        }
#pragma unroll
        for (int i = 0; i < 4; ++i)
#pragma unroll
            for (int j = 0; j < 4; ++j)
                acc[i][j] = __builtin_amdgcn_mfma_f32_16x16x32_bf16(af[i], bfr[j], acc[i][j], 0, 0, 0);
    }
    const int orow = (lane >> 4) * 4;
#pragma unroll
    for (int i = 0; i < 4; ++i)
#pragma unroll
        for (int j = 0; j < 4; ++j) {
            const int gc = gn0 + wn + j * 16 + lr;
            const float bv = bias[gc];
#pragma unroll
            for (int rr2 = 0; rr2 < 4; ++rr2) {
                const int gr = gm0 + wm + i * 16 + orow + rr2;
                if (gr < M) {
                    const float val = acc[i][j][rr2] + bv;
                    if constexpr (sizeof(OT) == 2) C[(size_t)gr * 512 + gc] = (OT)f2b(val);
                    else                           C[(size_t)gr * 512 + gc] = (OT)val;
                }
            }
        }
}

// -------- V transpose: vbT[b][h][d][k] = vb[b*740+k][h*64+d], k padded to 768 --------
__global__ __launch_bounds__(256) void transposeV(const u16* __restrict__ vb,
                                                  u16* __restrict__ vbT) {
    __shared__ u16 t[64][72];
    const int b = blockIdx.z, h = blockIdx.y, k0 = blockIdx.x * 64;
    const int tid = threadIdx.x;
    const size_t brow = (size_t)b * NTOK;
#pragma unroll
    for (int pass = 0; pass < 2; ++pass) {
        const int rr = pass * 32 + (tid >> 3);      // key within tile
        const int d8 = (tid & 7) * 8;
        const int key = k0 + rr;
        int4 v;
        if (key < NTOK) v = *(const int4*)(vb + (brow + key) * DM + h * 64 + d8);
        else v = int4{0, 0, 0, 0};
        *(int4*)&t[rr][d8] = v;
    }
    __syncthreads();
    const size_t obase = ((size_t)(b * MH + h) * 64) * KPAD + k0;
#pragma unroll
    for (int pass = 0; pass < 2; ++pass) {
        const int d = pass * 32 + (tid >> 3);       // 0..63
        const int k8 = (tid & 7) * 8;
        us4 o0, o1;
        o0.x = t[k8 + 0][d]; o0.y = t[k8 + 1][d]; o0.z = t[k8 + 2][d]; o0.w = t[k8 + 3][d];
        o1.x = t[k8 + 4][d]; o1.y = t[k8 + 5][d]; o1.z = t[k8 + 6][d]; o1.w = t[k8 + 7][d];
        *(us4*)(vbT + obase + (size_t)d * KPAD + k8) = o0;
        *(us4*)(vbT + obase + (size_t)d * KPAD + k8 + 4) = o1;
    }
}

// ---------------- MFMA flash-style attention ----------------
// One block per (b, h, 64-q tile). 4 waves x 16 q-rows.
template <bool TARGET>
__global__ __launch_bounds__(256) void attn_mfma(const u16* __restrict__ qb,
                                                 const u16* __restrict__ kb,
                                                 const u16* __restrict__ vbT,
                                                 const float* __restrict__ rpb,
                                                 const float* __restrict__ tt,
                                                 const float* __restrict__ tg,
                                                 u16* __restrict__ attb) {
    constexpr int NK   = TARGET ? NTOK : NTMP;
    constexpr int NC   = (NK + 31) / 32;            // 24 or 8 chunks
    constexpr int QTOT = TARGET ? NTGT : NTMP;
    constexpr int QOFF = TARGET ? NTMP : 0;
    constexpr int L    = TARGET ? 22 : 16;
    constexpr int RR   = 2 * L - 1;

    __shared__ u16 Ks[2][32][72];    // keys x d, padded rows (144B)
    __shared__ u16 VTs[2][64][40];   // d x keys, padded rows (80B)
    __shared__ u16 Pb[4][16][40];    // per-wave P: q x 32 keys, padded

    const int b = blockIdx.z, h = blockIdx.y;
    const int q0 = blockIdx.x * 64;
    const int tid = threadIdx.x;
    const int w = tid >> 6, lane = tid & 63;
    const int lq = lane & 15, lg = lane >> 4;       // q-col / group
    const size_t brow = (size_t)b * NTOK;

    // per-lane q (for Q frag cols and bias), clamped
    int qmine = q0 + w * 16 + lq;
    if (qmine > QTOT - 1) qmine = QTOT - 1;
    const int qh = qmine / L, qw = qmine % L;
    float tgv = 0.f;
    if constexpr (TARGET) tgv = tg[h * NTGT + qmine];

    // Q fragments (B-operand): col=lq, k=lg*8+e
    short8 qf[2];
#pragma unroll
    for (int dc = 0; dc < 2; ++dc)
        qf[dc] = *(const short8*)(qb + (brow + QOFF + qmine) * DM + h * 64 + dc * 32 + lg * 8);

    // staging coordinates
    const int krow = tid >> 3, kd8 = (tid & 7) * 8;     // K tile: 32 x 64
    const int vd = tid >> 2,  vk8 = (tid & 3) * 8;      // VT tile: 64 x 32
    const size_t vbase = ((size_t)(b * MH + h) * 64) * KPAD;

    float mrun = -1e30f, lrun = 0.f;
    f32x4 acc_o[4] = {};

    // prologue: stage chunk 0
    {
        const int key = krow;   // kc=0
        int4 kv = (key < NK) ? *(const int4*)(kb + (brow + key) * DM + h * 64 + kd8)
                             : int4{0, 0, 0, 0};
        *(int4*)&Ks[0][krow][kd8] = kv;
        int4 vv = *(const int4*)(vbT + vbase + (size_t)vd * KPAD + vk8);
        *(int4*)&VTs[0][vd][vk8] = vv;
    }
    __syncthreads();

    for (int kc = 0; kc < NC; ++kc) {
        const int cur = kc & 1, nxt = cur ^ 1;
        // issue next-chunk global loads early
        int4 nk_ = {0, 0, 0, 0}, nv_ = {0, 0, 0, 0};
        if (kc + 1 < NC) {
            const int key = (kc + 1) * 32 + krow;
            if (key < NK) nk_ = *(const int4*)(kb + (brow + key) * DM + h * 64 + kd8);
            nv_ = *(const int4*)(vbT + vbase + (size_t)vd * KPAD + (kc + 1) * 32 + vk8);
        }

        // ---- S^T tiles: rows=keys, cols=q ----
        f32x4 s[2] = {};
#pragma unroll
        for (int sub = 0; sub < 2; ++sub)
#pragma unroll
            for (int dc = 0; dc < 2; ++dc) {
                short8 ak = *(const short8*)&Ks[cur][sub * 16 + lq][dc * 32 + lg * 8];
                s[sub] = __builtin_amdgcn_mfma_f32_16x16x32_bf16(ak, qf[dc], s[sub], 0, 0, 0);
            }

        // ---- scale + bias + mask ----
        float sv[2][4];
#pragma unroll
        for (int sub = 0; sub < 2; ++sub)
#pragma unroll
            for (int r = 0; r < 4; ++r) {
                const int key = kc * 32 + sub * 16 + lg * 4 + r;
                float x = s[sub][r] * 0.125f;
                if constexpr (TARGET) {
                    if (key < NTMP) {
                        x += tt[h * NTMP + key] + tgv;
                    } else {
                        int kj = key - NTMP; if (kj > NTGT - 1) kj = NTGT - 1;
                        const int kh = kj / L, kw = kj % L;
                        x += rpb[((qh - kh + (L - 1)) * RR + (qw - kw + (L - 1))) * MH + h];
                    }
                    if (key >= NK) x = -1e30f;
                } else {
                    const int kh = key >> 4, kw = key & 15;
                    x += rpb[(qh - kh + (L - 1)) * RR + (qw - kw + (L - 1))];
                }
                sv[sub][r] = x;
            }

        // ---- online softmax (stats per q at lane&15) ----
        float cm = sv[0][0];
#pragma unroll
        for (int sub = 0; sub < 2; ++sub)
#pragma unroll
            for (int r = 0; r < 4; ++r) cm = fmaxf(cm, sv[sub][r]);
        cm = fmaxf(cm, __shfl_xor(cm, 16));
        cm = fmaxf(cm, __shfl_xor(cm, 32));
        const float mnew = fmaxf(mrun, cm);
        const float alpha = __expf(mrun - mnew);
        float psum = 0.f;
        us4 p0, p1;
        {
            float p[8];
#pragma unroll
            for (int sub = 0; sub < 2; ++sub)
#pragma unroll
                for (int r = 0; r < 4; ++r) {
                    const float e = __expf(sv[sub][r] - mnew);
                    p[sub * 4 + r] = e; psum += e;
                }
            p0.x = f2b(p[0]); p0.y = f2b(p[1]); p0.z = f2b(p[2]); p0.w = f2b(p[3]);
            p1.x = f2b(p[4]); p1.y = f2b(p[5]); p1.z = f2b(p[6]); p1.w = f2b(p[7]);
        }
        psum += __shfl_xor(psum, 16);
        psum += __shfl_xor(psum, 32);
        lrun = lrun * alpha + psum;
        mrun = mnew;

        // write P (q=lq rows; keys sub*16+lg*4..+3)
        *(us4*)&Pb[w][lq][lg * 4] = p0;
        *(us4*)&Pb[w][lq][16 + lg * 4] = p1;

        // rescale O (O rows q = lg*4+r -> fetch alpha via shfl from lane q)
        float af_[4];
#pragma unroll
        for (int r = 0; r < 4; ++r) af_[r] = __shfl(alpha, lg * 4 + r);
#pragma unroll
        for (int t = 0; t < 4; ++t)
#pragma unroll
            for (int r = 0; r < 4; ++r) acc_o[t][r] *= af_[r];

        // P visible within wave
        asm volatile("s_waitcnt lgkmcnt(0)" ::: "memory");

        // ---- PV: O[q][d] += P[q][32k] * V[32k][16d] ----
        short8 pf = *(const short8*)&Pb[w][lq][lg * 8];
#pragma unroll
        for (int t = 0; t < 4; ++t) {
            short8 vf = *(const short8*)&VTs[cur][t * 16 + lq][lg * 8];
            acc_o[t] = __builtin_amdgcn_mfma_f32_16x16x32_bf16(pf, vf, acc_o[t], 0, 0, 0);
        }

        // stage next chunk
        if (kc + 1 < NC) {
            *(int4*)&Ks[nxt][krow][kd8] = nk_;
            *(int4*)&VTs[nxt][vd][vk8] = nv_;
        }
        __syncthreads();
    }

    // epilogue: normalize, store (O rows q=lg*4+r, cols d=t*16+lq)
    float linv[4];
#pragma unroll
    for (int r = 0; r < 4; ++r) linv[r] = 1.f / __shfl(lrun, lg * 4 + r);
#pragma unroll
    for (int t = 0; t < 4; ++t)
#pragma unroll
        for (int r = 0; r < 4; ++r) {
            const int qrow = q0 + w * 16 + lg * 4 + r;
            if (qrow < QTOT)
                attb[(brow + QOFF + qrow) * DM + h * 64 + t * 16 + lq] = f2b(acc_o[t][r] * linv[r]);
        }
}

// ---------------- launch ----------------
extern "C" void kernel_launch(void* const* d_in, const int* in_sizes, int n_in,
                              void* d_out, int out_size, void* d_ws, size_t ws_size,
                              hipStream_t stream) {
    const float* x = (const float*)d_in[0];
    const float* convw[3] = {(const float*)d_in[1], (const float*)d_in[6], (const float*)d_in[11]};
    const float* bng[3]   = {(const float*)d_in[2], (const float*)d_in[7], (const float*)d_in[12]};
    const float* bnb[3]   = {(const float*)d_in[3], (const float*)d_in[8], (const float*)d_in[13]};
    const float* bnm[3]   = {(const float*)d_in[4], (const float*)d_in[9], (const float*)d_in[14]};
    const float* bnv[3]   = {(const float*)d_in[5], (const float*)d_in[10], (const float*)d_in[15]};
    const float* w[4]     = {(const float*)d_in[16], (const float*)d_in[18], (const float*)d_in[20], (const float*)d_in[22]};
    const float* bias[4]  = {(const float*)d_in[17], (const float*)d_in[19], (const float*)d_in[21], (const float*)d_in[23]};
    const float* rpb_t = (const float*)d_in[24];
    const float* rpb_m = (const float*)d_in[25];
    const float* tt    = (const float*)d_in[26];
    const float* tg    = (const float*)d_in[27];

    char* ws = (char*)d_ws;
    u16* wT[4];
    for (int i = 0; i < 4; ++i) wT[i] = (u16*)(ws + (size_t)i * 524288);
    const size_t SEQ = (size_t)MROWS * DM * 2;   // 12,124,160 B
    u16* cb  = (u16*)(ws + 2097152);
    u16* qb  = (u16*)(ws + 2097152 + SEQ);
    u16* kb  = (u16*)(ws + 2097152 + 2 * SEQ);
    u16* vb  = (u16*)(ws + 2097152 + 3 * SEQ);
    u16* vbT = (u16*)(ws + 2097152 + 4 * SEQ);   // 16*8*64*768*2 = 12.58 MB
    u16* attb = cb;   // cb is dead after the 3rd GEMM; reuse for attention output

    for (int i = 0; i < 4; ++i)
        transpose512<<<dim3(16, 16), dim3(32, 8), 0, stream>>>(w[i], wT[i]);

    u16* qkv[3] = {qb, kb, vb};
    for (int br = 0; br < 3; ++br) {
        conv_bn<<<MROWS, 256, 0, stream>>>(x, convw[br], bng[br], bnb[br], bnm[br], bnv[br], cb);
        gemm_bias<u16><<<dim3(93, 4), 256, 0, stream>>>(cb, wT[br], bias[br], qkv[br], MROWS);
    }
    transposeV<<<dim3(12, 8, 16), 256, 0, stream>>>(vb, vbT);
    attn_mfma<true><<<dim3(8, 8, 16), 256, 0, stream>>>(qb, kb, vbT, rpb_t, tt, tg, attb);
    attn_mfma<false><<<dim3(4, 8, 16), 256, 0, stream>>>(qb, kb, vbT, rpb_m, nullptr, nullptr, attb);
    gemm_bias<float><<<dim3(93, 4), 256, 0, stream>>>(attb, wT[3], bias[3], (float*)d_out, MROWS);
}